// Round 5
// baseline (271.290 us; speedup 1.0000x reference)
//
#include <hip/hip_runtime.h>
#include <math.h>

#define NN 100000
#define NE 3200000
#define NR 90
#define NB 782          // buckets of 128 nodes (dst>>7)
#define CH 4096         // edges per chunk
#define NCHUNK 782      // ceil(NE/CH)
#define CAP 6144        // padded per-bucket capacity (mean 4096, +32 sigma)

typedef unsigned int u32;
typedef unsigned short u16;

// ============ pass 1 (deterministic, ZERO global atomics) ============
// P1a: per-chunk histogram -> cntmat[chunk][NB]
__global__ __launch_bounds__(512) void count_kernel(const int* __restrict__ dst,
                                                    u32* __restrict__ cntmat) {
    __shared__ u32 cntA[NB];
    int tid = threadIdx.x;
    int c0 = blockIdx.x * CH;
    int c1 = c0 + CH; if (c1 > NE) c1 = NE;
    for (int i = tid; i < NB; i += 512) cntA[i] = 0;
    __syncthreads();
    for (int e = c0 + tid; e < c1; e += 512)
        atomicAdd(&cntA[(u32)dst[e] >> 7], 1u);
    __syncthreads();
    for (int i = tid; i < NB; i += 512)
        cntmat[(size_t)blockIdx.x * NB + i] = cntA[i];
}

// P1b: per-bucket exclusive scan over chunks -> offT[bucket][NCHUNK]; totals -> bucketcnt
__global__ __launch_bounds__(512) void scan_kernel(const u32* __restrict__ cntmat,
                                                   u32* __restrict__ offT,
                                                   u32* __restrict__ bucketcnt) {
    __shared__ u32 scanS[512];
    int tid = threadIdx.x, b = blockIdx.x;
    int c0 = 2 * tid, c1 = 2 * tid + 1;
    u32 a  = (c0 < NCHUNK) ? cntmat[(size_t)c0 * NB + b] : 0u;
    u32 bb = (c1 < NCHUNK) ? cntmat[(size_t)c1 * NB + b] : 0u;
    scanS[tid] = a + bb;
    __syncthreads();
#pragma unroll
    for (int ofs = 1; ofs < 512; ofs <<= 1) {
        u32 v = (tid >= ofs) ? scanS[tid - ofs] : 0u;
        __syncthreads();
        scanS[tid] += v;
        __syncthreads();
    }
    u32 excl = (tid == 0) ? 0u : scanS[tid - 1];
    if (c0 < NCHUNK) offT[(size_t)b * NCHUNK + c0] = excl;
    if (c1 < NCHUNK) offT[(size_t)b * NCHUNK + c1] = excl + a;
    if (tid == (NCHUNK - 1) / 2) bucketcnt[b] = scanS[(NCHUNK - 1) / 2];
}

// P1c: scatter with precomputed bases; LDS-staged coalesced global write
// tmp entry: (dst&127)<<25 | src<<7 | et ; bucket b's window is tmp[b*CAP ..]
__global__ __launch_bounds__(512) void scatter_kernel(const int* __restrict__ src,
                                                      const int* __restrict__ dst,
                                                      const int* __restrict__ et,
                                                      const u32* __restrict__ cntmat,
                                                      const u32* __restrict__ offT,
                                                      u32* __restrict__ tmp) {
    __shared__ u32 lcur[NB];
    __shared__ u32 delta[NB];
    __shared__ u32 scanS[512];
    __shared__ u32 lrecs[CH];
    __shared__ u16 lbid[CH];
    int tid = threadIdx.x, ck = blockIdx.x;
    int c0 = ck * CH;
    int c1 = c0 + CH; if (c1 > NE) c1 = NE;
    int nloc = c1 - c0;

    int i0 = 2 * tid, i1 = 2 * tid + 1;
    u32 ca = (i0 < NB) ? cntmat[(size_t)ck * NB + i0] : 0u;
    u32 cb = (i1 < NB) ? cntmat[(size_t)ck * NB + i1] : 0u;
    scanS[tid] = ca + cb;
    __syncthreads();
#pragma unroll
    for (int ofs = 1; ofs < 512; ofs <<= 1) {
        u32 v = (tid >= ofs) ? scanS[tid - ofs] : 0u;
        __syncthreads();
        scanS[tid] += v;
        __syncthreads();
    }
    u32 exc = (tid == 0) ? 0u : scanS[tid - 1];
    if (i0 < NB) {
        lcur[i0] = exc;
        delta[i0] = (u32)i0 * CAP + offT[(size_t)i0 * NCHUNK + ck] - exc;
    }
    if (i1 < NB) {
        u32 e1 = exc + ca;
        lcur[i1] = e1;
        delta[i1] = (u32)i1 * CAP + offT[(size_t)i1 * NCHUNK + ck] - e1;
    }
    __syncthreads();

    for (int e = c0 + tid; e < c1; e += 512) {
        u32 d = (u32)dst[e];
        u32 b = d >> 7;
        u32 pos = atomicAdd(&lcur[b], 1u);
        lrecs[pos] = ((d & 127u) << 25) | ((u32)src[e] << 7) | (u32)et[e];
        lbid[pos] = (u16)b;
    }
    __syncthreads();

    for (int k = tid; k < nloc; k += 512)
        tmp[delta[lbid[k]] + k] = lrecs[k];
}

// ---------------- pass 2 + layer 1 fused (512 threads, 128-node bucket) ----------------
#define CNTW (128 * 23)
__global__ __launch_bounds__(512) void pass2_kernel(const u32* __restrict__ tmp,
                                                    const u32* __restrict__ ccursor,
                                                    u32* __restrict__ off2,
                                                    u32* __restrict__ recs,
                                                    const float* __restrict__ x,
                                                    const float* __restrict__ w1,
                                                    const float* __restrict__ root1,
                                                    const float* __restrict__ b1,
                                                    float* __restrict__ h1) {
    __shared__ u32 lc2[128];         // per-node cursor (relative)
    __shared__ u32 cnt32[CNTW];      // per-(node,rel) u8 counts packed 4/word
    __shared__ u32 sh[128];          // inclusive degree scan (survives all phases)
    __shared__ u32 lrec[CAP];        // sorted recs mirror for phase E
    __shared__ float w1s[NR * 16];   // bank-rotated w1 (5.76 KB)
    int tid = threadIdx.x;
    int b = blockIdx.x;
    u32 r0 = (u32)b * CAP;
    u32 r1 = r0 + ccursor[b];

    for (int i = tid; i < CNTW; i += 512) cnt32[i] = 0;
    // stage w1 with per-t rotation: slot lin stores w1[t*16 + ((lin - 8*((t>>1)&1)) & 15)]
    for (int i = tid; i < NR * 16; i += 512) {
        int t = i >> 4, lin = i & 15;
        int rel = (lin - (((t >> 1) & 1) * 8)) & 15;
        w1s[i] = w1[t * 16 + rel];
    }
    __syncthreads();

    // A': issue ALL loads first (12 in flight), then consume with atomics
    u32 cached[12];
#pragma unroll
    for (int i = 0; i < 12; i++) {
        u32 k = r0 + (u32)tid + (u32)i * 512u;
        cached[i] = (k < r1) ? tmp[k] : 0xFFFFFFFFu;
    }
#pragma unroll
    for (int i = 0; i < 12; i++) {
        u32 v = cached[i];
        if (v != 0xFFFFFFFFu) {
            u32 ln = v >> 25, rel = v & 127u;
            atomicAdd(&cnt32[ln * 23 + (rel >> 2)], 1u << ((rel & 3u) * 8u));
        }
    }
    __syncthreads();

    // A2: per-node degree = bytewise sum of own 23-word slice
    if (tid < 128) {
        u32 s = 0;
#pragma unroll
        for (int i = 0; i < 23; i++) {
            u32 w = cnt32[tid * 23 + i];
            s += (w & 255u) + ((w >> 8) & 255u) + ((w >> 16) & 255u) + (w >> 24);
        }
        sh[tid] = s;
    }
    __syncthreads();

    // B: inclusive scan of degrees (128 entries)
#pragma unroll
    for (int ofs = 1; ofs < 128; ofs <<= 1) {
        u32 v = (tid >= ofs && tid < 128) ? sh[tid - ofs] : 0u;
        __syncthreads();
        if (tid < 128) sh[tid] += v;
        __syncthreads();
    }
    int n = b * 128 + tid;
    if (tid < 128) {
        u32 excl = (tid == 0) ? 0u : sh[tid - 1];
        u32 deg = sh[tid] - excl;
        if (n < NN) off2[n] = (deg << 23) | (r0 + excl);
        lc2[tid] = excl;
    }
    __syncthreads();

    // C: scatter final recs — embed count byte; mirror into LDS
#pragma unroll
    for (int i = 0; i < 12; i++) {
        u32 v = cached[i];
        if (v != 0xFFFFFFFFu) {
            u32 ln = v >> 25, rel = v & 127u;
            u32 c = (cnt32[ln * 23 + (rel >> 2)] >> ((rel & 3u) * 8u)) & 255u;
            u32 pos = atomicAdd(&lc2[ln], 1u);
            u32 rr = (c << 24) | (v & 0xFFFFFFu);
            recs[r0 + pos] = rr;
            lrec[pos] = rr;
        }
    }
    __syncthreads();

    // E: layer 1 — 16 lanes/node: 8 edge slots x 2 weight-blocks (lane j handles
    // inputs 2j..2j+1 -> outputs 4j..4j+3); recs+weights from LDS; distributed epilogue.
    for (int g = 0; g < 4; g++) {
        int ln = g * 32 + (tid >> 4);          // 0..127
        int l = tid & 15, e = l >> 1, j = l & 1;
        int nn = b * 128 + ln;
        float a0 = 0.f, a1 = 0.f, a2 = 0.f, a3 = 0.f;
        if (nn < NN) {
            u32 k0l = (ln == 0) ? 0u : sh[ln - 1];
            u32 k1l = sh[ln];
            for (u32 k = k0l + e; k < k1l; k += 8) {
                u32 rec = lrec[k];
                u32 t = rec & 127u, s = (rec >> 7) & 0x1FFFFu;
                float norm = 1.0f / (float)(rec >> 24);
                float2 xv = *(const float2*)(x + (size_t)s * 4 + 2 * j);
                const float* wq = w1s + t * 16 + (((j + ((t >> 1) & 1)) * 8) & 15);
                float4 wA = *(const float4*)wq;
                float4 wB = *(const float4*)(wq + 4);
                float x0 = xv.x * norm, x1 = xv.y * norm;
                a0 += x0 * wA.x + x1 * wB.x;
                a1 += x0 * wA.y + x1 * wB.y;
                a2 += x0 * wA.z + x1 * wB.z;
                a3 += x0 * wA.w + x1 * wB.w;
            }
        }
        a0 += __shfl_xor(a0, 2); a0 += __shfl_xor(a0, 4); a0 += __shfl_xor(a0, 8);
        a1 += __shfl_xor(a1, 2); a1 += __shfl_xor(a1, 4); a1 += __shfl_xor(a1, 8);
        a2 += __shfl_xor(a2, 2); a2 += __shfl_xor(a2, 4); a2 += __shfl_xor(a2, 8);
        a3 += __shfl_xor(a3, 2); a3 += __shfl_xor(a3, 4); a3 += __shfl_xor(a3, 8);
        if (e == 0 && nn < NN) {
            float4 xn = *(const float4*)(x + (size_t)nn * 4);
            int o0 = 4 * j;
            float4 o;
            o.x = fmaxf(a0 + b1[o0]     + xn.x * root1[o0]     + xn.y * root1[8 + o0]
                        + xn.z * root1[16 + o0]     + xn.w * root1[24 + o0], 0.f);
            o.y = fmaxf(a1 + b1[o0 + 1] + xn.x * root1[o0 + 1] + xn.y * root1[8 + o0 + 1]
                        + xn.z * root1[16 + o0 + 1] + xn.w * root1[24 + o0 + 1], 0.f);
            o.z = fmaxf(a2 + b1[o0 + 2] + xn.x * root1[o0 + 2] + xn.y * root1[8 + o0 + 2]
                        + xn.z * root1[16 + o0 + 2] + xn.w * root1[24 + o0 + 2], 0.f);
            o.w = fmaxf(a3 + b1[o0 + 3] + xn.x * root1[o0 + 3] + xn.y * root1[8 + o0 + 3]
                        + xn.z * root1[16 + o0 + 3] + xn.w * root1[24 + o0 + 3], 0.f);
            *(float4*)(h1 + (size_t)nn * 8 + 4 * j) = o;
        }
    }
}

// ======== layers 2/3: quad-per-edge along block-diagonal, LDS rotated weights ========

// ---------------- layer 2: add-aggr + root + bias + relu -> h2p f32[NN][16] ----------------
// lane j of each quad handles block j: inputs 2j..2j+1 -> outputs 3j..3j+2 (stored at 4j..4j+2)
__global__ __launch_bounds__(256) void layer2_kernel(
        const u32* __restrict__ off2, const u32* __restrict__ recs,
        const float* __restrict__ h1,            // [NN][8] f32
        const float* __restrict__ w2, const float* __restrict__ root2,
        const float* __restrict__ b2, float* __restrict__ h2p) {
    __shared__ float w2s[NR * 32];               // rotated, 6->8 padded (11.5 KB)
    int tid = threadIdx.x;
    for (int i = tid; i < NR * 32; i += 256) {
        int t = i >> 5, lin = i & 31;
        int rel = (lin - ((t * 8) & 31)) & 31;   // = 8*j + slot
        int jj = rel >> 3, slot = rel & 7;
        w2s[i] = (slot < 6) ? w2[t * 24 + jj * 6 + slot] : 0.0f;
    }
    __syncthreads();

    int gid = blockIdx.x * 256 + tid;
    int n = gid >> 4, l = gid & 15, e = l >> 2, j = l & 3;
    if (n >= NN) return;
    u32 ov = off2[n];
    u32 k0 = ov & 0x7FFFFFu, k1 = k0 + (ov >> 23);
    float a0 = 0.f, a1 = 0.f, a2 = 0.f;
    for (u32 k = k0 + e; k < k1; k += 4) {
        u32 rec = recs[k];
        u32 t = rec & 127u, s = (rec >> 7) & 0x1FFFFu;
        float2 hv = *(const float2*)(h1 + (size_t)s * 8 + 2 * j);
        const float* wq = w2s + t * 32 + ((8 * (j + t)) & 31);
        float4 wa = *(const float4*)wq;          // slots 0..3
        float2 wb = *(const float2*)(wq + 4);    // slots 4..5
        a0 += hv.x * wa.x + hv.y * wa.w;
        a1 += hv.x * wa.y + hv.y * wb.x;
        a2 += hv.x * wa.z + hv.y * wb.y;
    }
    a0 += __shfl_xor(a0, 4); a0 += __shfl_xor(a0, 8);
    a1 += __shfl_xor(a1, 4); a1 += __shfl_xor(a1, 8);
    a2 += __shfl_xor(a2, 4); a2 += __shfl_xor(a2, 8);
    if (e == 0) {
        float4 xa = *(const float4*)(h1 + (size_t)n * 8);
        float4 xb = *(const float4*)(h1 + (size_t)n * 8 + 4);
        float hv8[8] = {xa.x, xa.y, xa.z, xa.w, xb.x, xb.y, xb.z, xb.w};
        float accv[3] = {a0, a1, a2};
        int o0 = 3 * j;
        float4 res;
        float* rp = (float*)&res;
#pragma unroll
        for (int c = 0; c < 3; c++) {
            float v = accv[c] + b2[o0 + c];
#pragma unroll
            for (int i2 = 0; i2 < 8; i2++) v += hv8[i2] * root2[i2 * 12 + o0 + c];
            rp[c] = fmaxf(v, 0.0f);
        }
        rp[3] = 0.0f;
        *(float4*)(h2p + (size_t)n * 16 + 4 * j) = res;
    }
}

// ---------------- layer 3: mean-aggr + root + bias + log_softmax ----------------
// lane j handles inputs 3j..3j+2 (h2p slots 4j..4j+2) -> partial outputs 2(j>>1), 2(j>>1)+1
__global__ __launch_bounds__(256) void layer3_kernel(
        const u32* __restrict__ off2, const u32* __restrict__ recs,
        const float* __restrict__ h2p,           // [NN][16] f32 padded
        const float* __restrict__ w3, const float* __restrict__ root3,
        const float* __restrict__ b3, float* __restrict__ out) {
    __shared__ float w3s[NR * 32];               // rotated, 6->8 padded (11.5 KB)
    int tid = threadIdx.x;
    for (int i = tid; i < NR * 32; i += 256) {
        int t = i >> 5, lin = i & 31;
        int rel = (lin - ((t * 8) & 31)) & 31;
        int jj = rel >> 3, slot = rel & 7;
        w3s[i] = (slot < 6) ? w3[t * 24 + jj * 6 + slot] : 0.0f;
    }
    __syncthreads();

    int gid = blockIdx.x * 256 + tid;
    int n = gid >> 4, l = gid & 15, e = l >> 2, j = l & 3;
    if (n >= NN) return;
    float a0 = 0.f, a1 = 0.f;
    u32 ov = off2[n];
    u32 k0 = ov & 0x7FFFFFu, k1 = k0 + (ov >> 23);
    for (u32 k = k0 + e; k < k1; k += 4) {
        u32 rec = recs[k];
        u32 t = rec & 127u, s = (rec >> 7) & 0x1FFFFu;
        float norm = 1.0f / (float)(rec >> 24);
        float4 hp = *(const float4*)(h2p + (size_t)s * 16 + 4 * j);
        const float* wq = w3s + t * 32 + ((8 * (j + t)) & 31);
        float4 wa = *(const float4*)wq;          // slots 0..3: i0o0 i0o1 i1o0 i1o1
        float2 wb = *(const float2*)(wq + 4);    // slots 4..5: i2o0 i2o1
        float m0 = hp.x * wa.x + hp.y * wa.z + hp.z * wb.x;
        float m1 = hp.x * wa.y + hp.y * wa.w + hp.z * wb.y;
        a0 += m0 * norm;
        a1 += m1 * norm;
    }
    // reduce over edge slots, then merge the two input-halves (j and j^1 share output block)
    a0 += __shfl_xor(a0, 4); a0 += __shfl_xor(a0, 8); a0 += __shfl_xor(a0, 1);
    a1 += __shfl_xor(a1, 4); a1 += __shfl_xor(a1, 8); a1 += __shfl_xor(a1, 1);
    if (e == 0 && (j & 1) == 0) {
        int bb = j >> 1;                          // outputs 2bb, 2bb+1
        float4 q0 = *(const float4*)(h2p + (size_t)n * 16);
        float4 q1 = *(const float4*)(h2p + (size_t)n * 16 + 4);
        float4 q2 = *(const float4*)(h2p + (size_t)n * 16 + 8);
        float4 q3 = *(const float4*)(h2p + (size_t)n * 16 + 12);
        float hv[12] = {q0.x, q0.y, q0.z, q1.x, q1.y, q1.z,
                        q2.x, q2.y, q2.z, q3.x, q3.y, q3.z};
        float v0 = a0 + b3[2 * bb], v1 = a1 + b3[2 * bb + 1];
#pragma unroll
        for (int f = 0; f < 12; f++) {
            v0 += hv[f] * root3[f * 4 + 2 * bb];
            v1 += hv[f] * root3[f * 4 + 2 * bb + 1];
        }
        float mx = fmaxf(v0, v1);
        mx = fmaxf(mx, __shfl_xor(mx, 2));
        float sm = __expf(v0 - mx) + __expf(v1 - mx);
        sm += __shfl_xor(sm, 2);
        float lse = mx + __logf(sm);
        *(float2*)(out + (size_t)n * 4 + 2 * bb) = make_float2(v0 - lse, v1 - lse);
    }
}

extern "C" void kernel_launch(void* const* d_in, const int* in_sizes, int n_in,
                              void* d_out, int out_size, void* d_ws, size_t ws_size,
                              hipStream_t stream) {
    const float* x     = (const float*)d_in[0];
    const int*   ei    = (const int*)d_in[1];   // [2, E]
    const int*   etype = (const int*)d_in[2];
    const float* w1    = (const float*)d_in[3];
    const float* root1 = (const float*)d_in[4];
    const float* b1    = (const float*)d_in[5];
    const float* w2    = (const float*)d_in[6];
    const float* root2 = (const float*)d_in[7];
    const float* b2    = (const float*)d_in[8];
    const float* w3    = (const float*)d_in[9];
    const float* root3 = (const float*)d_in[10];
    const float* b3    = (const float*)d_in[11];
    float* out = (float*)d_out;

    const int* src = ei;
    const int* dst = ei + NE;

    // workspace layout (bytes):
    //   bucketcnt: [NB]     u32   @ 0           (3,128 -> pad 3,200)
    //   off2    : [NN]      u32   @ 3,200       (400,000 -> ends 403,200)
    //   tmp     : [NB*CAP]  u32   @ 403,200     (19,218,432 -> ends 19,621,632)
    //     h2p   : [NN][16]  f32   @ 403,200     (6,400,000) -- overlays tmp (dead after pass2)
    //   recs    : [NB*CAP]  u32   @ 19,621,632  (19,218,432 -> ends 38,840,064)
    //     cntmat: [NCHUNK*NB] u32 @ 19,621,632  (2,446,096) -- overlays recs, dead after P1c
    //     offT  : [NB*NCHUNK] u32 @ 22,067,728  (2,446,096) -- overlays recs, dead after P1c
    //   h1      : [NN][8]   f32   @ 38,840,064  (3,200,000 -> total 42,040,064)
    char* ws = (char*)d_ws;
    u32*   bucketcnt = (u32*)ws;
    u32*   off2    = (u32*)(ws + 3200);
    u32*   tmp     = (u32*)(ws + 403200);
    float* h2p     = (float*)(ws + 403200);
    u32*   recs    = (u32*)(ws + 19621632);
    u32*   cntmat  = (u32*)(ws + 19621632);
    u32*   offT    = (u32*)(ws + 22067728);
    float* h1      = (float*)(ws + 38840064);

    dim3 pgrid(NCHUNK);                      // 782
    dim3 ngrid(NB);                          // 782
    dim3 lgrid((NN * 16 + 255) / 256);       // 6250 (16 lanes/node, quad-per-edge)

    count_kernel<<<pgrid, 512, 0, stream>>>(dst, cntmat);
    scan_kernel<<<dim3(NB), 512, 0, stream>>>(cntmat, offT, bucketcnt);
    scatter_kernel<<<pgrid, 512, 0, stream>>>(src, dst, etype, cntmat, offT, tmp);
    pass2_kernel<<<ngrid, 512, 0, stream>>>(tmp, bucketcnt, off2, recs, x, w1, root1, b1, h1);
    layer2_kernel<<<lgrid, 256, 0, stream>>>(off2, recs, h1, w2, root2, b2, h2p);
    layer3_kernel<<<lgrid, 256, 0, stream>>>(off2, recs, h2p, w3, root3, b3, out);
}

// Round 6
// 237.247 us; speedup vs baseline: 1.1435x; 1.1435x over previous
//
#include <hip/hip_runtime.h>
#include <math.h>

#define NN 100000
#define NE 3200000
#define NR 90
#define NB 782          // buckets of 128 nodes (dst>>7)
#define CH 4096         // edges per chunk
#define NCHUNK 782      // ceil(NE/CH)
#define CAP 6144        // padded per-bucket capacity (mean 4096, +32 sigma)

typedef unsigned int u32;
typedef unsigned short u16;

__device__ inline u32 pack2(float a, float b) {       // bf16(a) lo16, bf16(b) hi16 (RNE)
    u32 ua = __float_as_uint(a); ua += 0x7FFFu + ((ua >> 16) & 1u);
    u32 ub = __float_as_uint(b); ub += 0x7FFFu + ((ub >> 16) & 1u);
    return (ua >> 16) | (ub & 0xFFFF0000u);
}
__device__ inline float unlo(u32 w) { return __uint_as_float(w << 16); }
__device__ inline float unhi(u32 w) { return __uint_as_float(w & 0xFFFF0000u); }

// ============ pass 1 (deterministic, ZERO global atomics) ============
// P1a: per-chunk histogram -> cntmat[chunk][NB]
__global__ __launch_bounds__(512) void count_kernel(const int* __restrict__ dst,
                                                    u32* __restrict__ cntmat) {
    __shared__ u32 cntA[NB];
    int tid = threadIdx.x;
    int c0 = blockIdx.x * CH;
    int c1 = c0 + CH; if (c1 > NE) c1 = NE;
    for (int i = tid; i < NB; i += 512) cntA[i] = 0;
    __syncthreads();
    for (int e = c0 + tid; e < c1; e += 512)
        atomicAdd(&cntA[(u32)dst[e] >> 7], 1u);
    __syncthreads();
    for (int i = tid; i < NB; i += 512)
        cntmat[(size_t)blockIdx.x * NB + i] = cntA[i];
}

// P1b: per-bucket exclusive scan over chunks -> offT[bucket][NCHUNK]; totals -> bucketcnt
__global__ __launch_bounds__(512) void scan_kernel(const u32* __restrict__ cntmat,
                                                   u32* __restrict__ offT,
                                                   u32* __restrict__ bucketcnt) {
    __shared__ u32 scanS[512];
    int tid = threadIdx.x, b = blockIdx.x;
    int c0 = 2 * tid, c1 = 2 * tid + 1;
    u32 a  = (c0 < NCHUNK) ? cntmat[(size_t)c0 * NB + b] : 0u;
    u32 bb = (c1 < NCHUNK) ? cntmat[(size_t)c1 * NB + b] : 0u;
    scanS[tid] = a + bb;
    __syncthreads();
#pragma unroll
    for (int ofs = 1; ofs < 512; ofs <<= 1) {
        u32 v = (tid >= ofs) ? scanS[tid - ofs] : 0u;
        __syncthreads();
        scanS[tid] += v;
        __syncthreads();
    }
    u32 excl = (tid == 0) ? 0u : scanS[tid - 1];
    if (c0 < NCHUNK) offT[(size_t)b * NCHUNK + c0] = excl;
    if (c1 < NCHUNK) offT[(size_t)b * NCHUNK + c1] = excl + a;
    if (tid == (NCHUNK - 1) / 2) bucketcnt[b] = scanS[(NCHUNK - 1) / 2];
}

// P1c: scatter with precomputed bases; LDS-staged coalesced global write
// tmp entry: (dst&127)<<25 | src<<7 | et ; bucket b's window is tmp[b*CAP ..]
__global__ __launch_bounds__(512) void scatter_kernel(const int* __restrict__ src,
                                                      const int* __restrict__ dst,
                                                      const int* __restrict__ et,
                                                      const u32* __restrict__ cntmat,
                                                      const u32* __restrict__ offT,
                                                      u32* __restrict__ tmp) {
    __shared__ u32 lcur[NB];
    __shared__ u32 delta[NB];
    __shared__ u32 scanS[512];
    __shared__ u32 lrecs[CH];
    __shared__ u16 lbid[CH];
    int tid = threadIdx.x, ck = blockIdx.x;
    int c0 = ck * CH;
    int c1 = c0 + CH; if (c1 > NE) c1 = NE;
    int nloc = c1 - c0;

    int i0 = 2 * tid, i1 = 2 * tid + 1;
    u32 ca = (i0 < NB) ? cntmat[(size_t)ck * NB + i0] : 0u;
    u32 cb = (i1 < NB) ? cntmat[(size_t)ck * NB + i1] : 0u;
    scanS[tid] = ca + cb;
    __syncthreads();
#pragma unroll
    for (int ofs = 1; ofs < 512; ofs <<= 1) {
        u32 v = (tid >= ofs) ? scanS[tid - ofs] : 0u;
        __syncthreads();
        scanS[tid] += v;
        __syncthreads();
    }
    u32 exc = (tid == 0) ? 0u : scanS[tid - 1];
    if (i0 < NB) {
        lcur[i0] = exc;
        delta[i0] = (u32)i0 * CAP + offT[(size_t)i0 * NCHUNK + ck] - exc;
    }
    if (i1 < NB) {
        u32 e1 = exc + ca;
        lcur[i1] = e1;
        delta[i1] = (u32)i1 * CAP + offT[(size_t)i1 * NCHUNK + ck] - e1;
    }
    __syncthreads();

    for (int e = c0 + tid; e < c1; e += 512) {
        u32 d = (u32)dst[e];
        u32 b = d >> 7;
        u32 pos = atomicAdd(&lcur[b], 1u);
        lrecs[pos] = ((d & 127u) << 25) | ((u32)src[e] << 7) | (u32)et[e];
        lbid[pos] = (u16)b;
    }
    __syncthreads();

    for (int k = tid; k < nloc; k += 512)
        tmp[delta[lbid[k]] + k] = lrecs[k];
}

// ---------------- pass 2 + layer 1 fused (512 threads, 128-node bucket) ----------------
#define CNTW (128 * 23)
__global__ __launch_bounds__(512) void pass2_kernel(const u32* __restrict__ tmp,
                                                    const u32* __restrict__ ccursor,
                                                    u32* __restrict__ off2,
                                                    u32* __restrict__ recs,
                                                    const float* __restrict__ x,
                                                    const float* __restrict__ w1,
                                                    const float* __restrict__ root1,
                                                    const float* __restrict__ b1,
                                                    u32* __restrict__ h1b) {   // [NN][4] u32 (8 bf16)
    __shared__ u32 lc2[128];         // per-node cursor (relative)
    __shared__ u32 cnt32[CNTW];      // per-(node,rel) u8 counts packed 4/word
    __shared__ u32 sh[128];          // inclusive degree scan (survives all phases)
    __shared__ u32 lrec[CAP];        // sorted recs mirror for phase E
    __shared__ float w1s[NR * 16];   // bank-rotated w1 (5.76 KB)
    int tid = threadIdx.x;
    int b = blockIdx.x;
    u32 r0 = (u32)b * CAP;
    u32 r1 = r0 + ccursor[b];

    for (int i = tid; i < CNTW; i += 512) cnt32[i] = 0;
    // stage w1 with per-t rotation: slot lin stores w1[t*16 + ((lin - 8*((t>>1)&1)) & 15)]
    for (int i = tid; i < NR * 16; i += 512) {
        int t = i >> 4, lin = i & 15;
        int rel = (lin - (((t >> 1) & 1) * 8)) & 15;
        w1s[i] = w1[t * 16 + rel];
    }
    __syncthreads();

    // A': issue ALL loads first (12 in flight), then consume with atomics
    u32 cached[12];
#pragma unroll
    for (int i = 0; i < 12; i++) {
        u32 k = r0 + (u32)tid + (u32)i * 512u;
        cached[i] = (k < r1) ? tmp[k] : 0xFFFFFFFFu;
    }
#pragma unroll
    for (int i = 0; i < 12; i++) {
        u32 v = cached[i];
        if (v != 0xFFFFFFFFu) {
            u32 ln = v >> 25, rel = v & 127u;
            atomicAdd(&cnt32[ln * 23 + (rel >> 2)], 1u << ((rel & 3u) * 8u));
        }
    }
    __syncthreads();

    // A2: per-node degree = bytewise sum of own 23-word slice
    if (tid < 128) {
        u32 s = 0;
#pragma unroll
        for (int i = 0; i < 23; i++) {
            u32 w = cnt32[tid * 23 + i];
            s += (w & 255u) + ((w >> 8) & 255u) + ((w >> 16) & 255u) + (w >> 24);
        }
        sh[tid] = s;
    }
    __syncthreads();

    // B: inclusive scan of degrees (128 entries)
#pragma unroll
    for (int ofs = 1; ofs < 128; ofs <<= 1) {
        u32 v = (tid >= ofs && tid < 128) ? sh[tid - ofs] : 0u;
        __syncthreads();
        if (tid < 128) sh[tid] += v;
        __syncthreads();
    }
    int n = b * 128 + tid;
    if (tid < 128) {
        u32 excl = (tid == 0) ? 0u : sh[tid - 1];
        u32 deg = sh[tid] - excl;
        if (n < NN) off2[n] = (deg << 23) | (r0 + excl);
        lc2[tid] = excl;
    }
    __syncthreads();

    // C: scatter final recs — embed count byte; mirror into LDS
#pragma unroll
    for (int i = 0; i < 12; i++) {
        u32 v = cached[i];
        if (v != 0xFFFFFFFFu) {
            u32 ln = v >> 25, rel = v & 127u;
            u32 c = (cnt32[ln * 23 + (rel >> 2)] >> ((rel & 3u) * 8u)) & 255u;
            u32 pos = atomicAdd(&lc2[ln], 1u);
            u32 rr = (c << 24) | (v & 0xFFFFFFu);
            recs[r0 + pos] = rr;
            lrec[pos] = rr;
        }
    }
    __syncthreads();

    // E: layer 1 — 16 lanes/node: 8 edge slots x 2 weight-blocks; distributed bf16 epilogue
    for (int g = 0; g < 4; g++) {
        int ln = g * 32 + (tid >> 4);          // 0..127
        int l = tid & 15, e = l >> 1, j = l & 1;
        int nn = b * 128 + ln;
        float a0 = 0.f, a1 = 0.f, a2 = 0.f, a3 = 0.f;
        if (nn < NN) {
            u32 k0l = (ln == 0) ? 0u : sh[ln - 1];
            u32 k1l = sh[ln];
            for (u32 k = k0l + e; k < k1l; k += 8) {
                u32 rec = lrec[k];
                u32 t = rec & 127u, s = (rec >> 7) & 0x1FFFFu;
                float norm = 1.0f / (float)(rec >> 24);
                float2 xv = *(const float2*)(x + (size_t)s * 4 + 2 * j);
                const float* wq = w1s + t * 16 + (((j + ((t >> 1) & 1)) * 8) & 15);
                float4 wA = *(const float4*)wq;
                float4 wB = *(const float4*)(wq + 4);
                float x0 = xv.x * norm, x1 = xv.y * norm;
                a0 += x0 * wA.x + x1 * wB.x;
                a1 += x0 * wA.y + x1 * wB.y;
                a2 += x0 * wA.z + x1 * wB.z;
                a3 += x0 * wA.w + x1 * wB.w;
            }
        }
        a0 += __shfl_xor(a0, 2); a0 += __shfl_xor(a0, 4); a0 += __shfl_xor(a0, 8);
        a1 += __shfl_xor(a1, 2); a1 += __shfl_xor(a1, 4); a1 += __shfl_xor(a1, 8);
        a2 += __shfl_xor(a2, 2); a2 += __shfl_xor(a2, 4); a2 += __shfl_xor(a2, 8);
        a3 += __shfl_xor(a3, 2); a3 += __shfl_xor(a3, 4); a3 += __shfl_xor(a3, 8);
        if (e == 0 && nn < NN) {
            float4 xn = *(const float4*)(x + (size_t)nn * 4);
            int o0 = 4 * j;
            float v0 = fmaxf(a0 + b1[o0]     + xn.x * root1[o0]     + xn.y * root1[8 + o0]
                        + xn.z * root1[16 + o0]     + xn.w * root1[24 + o0], 0.f);
            float v1 = fmaxf(a1 + b1[o0 + 1] + xn.x * root1[o0 + 1] + xn.y * root1[8 + o0 + 1]
                        + xn.z * root1[16 + o0 + 1] + xn.w * root1[24 + o0 + 1], 0.f);
            float v2 = fmaxf(a2 + b1[o0 + 2] + xn.x * root1[o0 + 2] + xn.y * root1[8 + o0 + 2]
                        + xn.z * root1[16 + o0 + 2] + xn.w * root1[24 + o0 + 2], 0.f);
            float v3 = fmaxf(a3 + b1[o0 + 3] + xn.x * root1[o0 + 3] + xn.y * root1[8 + o0 + 3]
                        + xn.z * root1[16 + o0 + 3] + xn.w * root1[24 + o0 + 3], 0.f);
            *(uint2*)(h1b + (size_t)nn * 4 + 2 * j) = make_uint2(pack2(v0, v1), pack2(v2, v3));
        }
    }
}

// ======== layers 2/3: quad-per-edge, bf16 L2-resident tables, LDS rotated weights ========

// ---------------- layer 2: add-aggr + root + bias + relu -> h2b bf16[NN][16] ----------------
// lane j of each quad handles block j: inputs 2j..2j+1 -> outputs 3j..3j+2 (u32 words 2j,2j+1)
__global__ __launch_bounds__(256) void layer2_kernel(
        const u32* __restrict__ off2, const u32* __restrict__ recs,
        const u32* __restrict__ h1b,             // [NN][4] u32 (8 bf16)
        const float* __restrict__ w2, const float* __restrict__ root2,
        const float* __restrict__ b2, u32* __restrict__ h2b) {   // [NN][8] u32 (16 bf16 slots)
    __shared__ float w2s[NR * 32];               // rotated, 6->8 padded (11.5 KB)
    int tid = threadIdx.x;
    for (int i = tid; i < NR * 32; i += 256) {
        int t = i >> 5, lin = i & 31;
        int rel = (lin - ((t * 8) & 31)) & 31;   // = 8*j + slot
        int jj = rel >> 3, slot = rel & 7;
        w2s[i] = (slot < 6) ? w2[t * 24 + jj * 6 + slot] : 0.0f;
    }
    __syncthreads();

    int gid = blockIdx.x * 256 + tid;
    int n = gid >> 4, l = gid & 15, e = l >> 2, j = l & 3;
    if (n >= NN) return;
    u32 ov = off2[n];
    u32 k0 = ov & 0x7FFFFFu, k1 = k0 + (ov >> 23);
    float a0 = 0.f, a1 = 0.f, a2 = 0.f;
#pragma unroll 2
    for (u32 k = k0 + e; k < k1; k += 4) {
        u32 rec = recs[k];
        u32 t = rec & 127u, s = (rec >> 7) & 0x1FFFFu;
        u32 hw = h1b[(size_t)s * 4 + j];          // feats 2j, 2j+1 (bf16 pair)
        float hx = unlo(hw), hy = unhi(hw);
        const float* wq = w2s + t * 32 + ((8 * (j + t)) & 31);
        float4 wa = *(const float4*)wq;          // slots 0..3
        float2 wb = *(const float2*)(wq + 4);    // slots 4..5
        a0 += hx * wa.x + hy * wa.w;
        a1 += hx * wa.y + hy * wb.x;
        a2 += hx * wa.z + hy * wb.y;
    }
    a0 += __shfl_xor(a0, 4); a0 += __shfl_xor(a0, 8);
    a1 += __shfl_xor(a1, 4); a1 += __shfl_xor(a1, 8);
    a2 += __shfl_xor(a2, 4); a2 += __shfl_xor(a2, 8);
    if (e == 0) {
        uint4 hn = *(const uint4*)(h1b + (size_t)n * 4);
        float hv8[8] = { unlo(hn.x), unhi(hn.x), unlo(hn.y), unhi(hn.y),
                         unlo(hn.z), unhi(hn.z), unlo(hn.w), unhi(hn.w) };
        float accv[3] = {a0, a1, a2};
        int o0 = 3 * j;
        float rv[3];
#pragma unroll
        for (int c = 0; c < 3; c++) {
            float v = accv[c] + b2[o0 + c];
#pragma unroll
            for (int i2 = 0; i2 < 8; i2++) v += hv8[i2] * root2[i2 * 12 + o0 + c];
            rv[c] = fmaxf(v, 0.0f);
        }
        *(uint2*)(h2b + (size_t)n * 8 + 2 * j) =
            make_uint2(pack2(rv[0], rv[1]), pack2(rv[2], 0.0f));
    }
}

// ---------------- layer 3: mean-aggr + root + bias + log_softmax ----------------
// lane j handles inputs 3j..3j+2 (u32 words 2j,2j+1) -> partial outputs 2(j>>1), 2(j>>1)+1
__global__ __launch_bounds__(256) void layer3_kernel(
        const u32* __restrict__ off2, const u32* __restrict__ recs,
        const u32* __restrict__ h2b,             // [NN][8] u32 (16 bf16 slots)
        const float* __restrict__ w3, const float* __restrict__ root3,
        const float* __restrict__ b3, float* __restrict__ out) {
    __shared__ float w3s[NR * 32];               // rotated, 6->8 padded (11.5 KB)
    int tid = threadIdx.x;
    for (int i = tid; i < NR * 32; i += 256) {
        int t = i >> 5, lin = i & 31;
        int rel = (lin - ((t * 8) & 31)) & 31;
        int jj = rel >> 3, slot = rel & 7;
        w3s[i] = (slot < 6) ? w3[t * 24 + jj * 6 + slot] : 0.0f;
    }
    __syncthreads();

    int gid = blockIdx.x * 256 + tid;
    int n = gid >> 4, l = gid & 15, e = l >> 2, j = l & 3;
    if (n >= NN) return;
    float a0 = 0.f, a1 = 0.f;
    u32 ov = off2[n];
    u32 k0 = ov & 0x7FFFFFu, k1 = k0 + (ov >> 23);
#pragma unroll 2
    for (u32 k = k0 + e; k < k1; k += 4) {
        u32 rec = recs[k];
        u32 t = rec & 127u, s = (rec >> 7) & 0x1FFFFu;
        float norm = 1.0f / (float)(rec >> 24);
        uint2 hp = *(const uint2*)(h2b + (size_t)s * 8 + 2 * j);   // 3 bf16 feats
        float h0 = unlo(hp.x), h1v = unhi(hp.x), h2v = unlo(hp.y);
        const float* wq = w3s + t * 32 + ((8 * (j + t)) & 31);
        float4 wa = *(const float4*)wq;          // slots 0..3: i0o0 i0o1 i1o0 i1o1
        float2 wb = *(const float2*)(wq + 4);    // slots 4..5: i2o0 i2o1
        float m0 = h0 * wa.x + h1v * wa.z + h2v * wb.x;
        float m1 = h0 * wa.y + h1v * wa.w + h2v * wb.y;
        a0 += m0 * norm;
        a1 += m1 * norm;
    }
    // reduce over edge slots, then merge the two input-halves (j and j^1 share output block)
    a0 += __shfl_xor(a0, 4); a0 += __shfl_xor(a0, 8); a0 += __shfl_xor(a0, 1);
    a1 += __shfl_xor(a1, 4); a1 += __shfl_xor(a1, 8); a1 += __shfl_xor(a1, 1);
    if (e == 0 && (j & 1) == 0) {
        int bb = j >> 1;                          // outputs 2bb, 2bb+1
        const u32* hbn = h2b + (size_t)n * 8;
        uint4 q0 = *(const uint4*)hbn;
        uint4 q1 = *(const uint4*)(hbn + 4);
        float hv[12] = { unlo(q0.x), unhi(q0.x), unlo(q0.y),
                         unlo(q0.z), unhi(q0.z), unlo(q0.w),
                         unlo(q1.x), unhi(q1.x), unlo(q1.y),
                         unlo(q1.z), unhi(q1.z), unlo(q1.w) };
        float v0 = a0 + b3[2 * bb], v1 = a1 + b3[2 * bb + 1];
#pragma unroll
        for (int f = 0; f < 12; f++) {
            v0 += hv[f] * root3[f * 4 + 2 * bb];
            v1 += hv[f] * root3[f * 4 + 2 * bb + 1];
        }
        float mx = fmaxf(v0, v1);
        mx = fmaxf(mx, __shfl_xor(mx, 2));
        float sm = __expf(v0 - mx) + __expf(v1 - mx);
        sm += __shfl_xor(sm, 2);
        float lse = mx + __logf(sm);
        *(float2*)(out + (size_t)n * 4 + 2 * bb) = make_float2(v0 - lse, v1 - lse);
    }
}

extern "C" void kernel_launch(void* const* d_in, const int* in_sizes, int n_in,
                              void* d_out, int out_size, void* d_ws, size_t ws_size,
                              hipStream_t stream) {
    const float* x     = (const float*)d_in[0];
    const int*   ei    = (const int*)d_in[1];   // [2, E]
    const int*   etype = (const int*)d_in[2];
    const float* w1    = (const float*)d_in[3];
    const float* root1 = (const float*)d_in[4];
    const float* b1    = (const float*)d_in[5];
    const float* w2    = (const float*)d_in[6];
    const float* root2 = (const float*)d_in[7];
    const float* b2    = (const float*)d_in[8];
    const float* w3    = (const float*)d_in[9];
    const float* root3 = (const float*)d_in[10];
    const float* b3    = (const float*)d_in[11];
    float* out = (float*)d_out;

    const int* src = ei;
    const int* dst = ei + NE;

    // workspace layout (bytes):
    //   bucketcnt: [NB]     u32   @ 0           (3,128 -> pad 3,200)
    //   off2    : [NN]      u32   @ 3,200       (400,000 -> ends 403,200)
    //   tmp     : [NB*CAP]  u32   @ 403,200     (19,218,432 -> ends 19,621,632)
    //     h2b   : [NN][8]   u32   @ 403,200     (3,200,000) -- overlays tmp (dead after pass2)
    //   recs    : [NB*CAP]  u32   @ 19,621,632  (19,218,432 -> ends 38,840,064)
    //     cntmat: [NCHUNK*NB] u32 @ 19,621,632  (2,446,096) -- overlays recs, dead after P1c
    //     offT  : [NB*NCHUNK] u32 @ 22,067,728  (2,446,096) -- overlays recs, dead after P1c
    //   h1b     : [NN][4]   u32   @ 38,840,064  (1,600,000 -> total 40,440,064)
    char* ws = (char*)d_ws;
    u32*   bucketcnt = (u32*)ws;
    u32*   off2    = (u32*)(ws + 3200);
    u32*   tmp     = (u32*)(ws + 403200);
    u32*   h2b     = (u32*)(ws + 403200);
    u32*   recs    = (u32*)(ws + 19621632);
    u32*   cntmat  = (u32*)(ws + 19621632);
    u32*   offT    = (u32*)(ws + 22067728);
    u32*   h1b     = (u32*)(ws + 38840064);

    dim3 pgrid(NCHUNK);                      // 782
    dim3 ngrid(NB);                          // 782
    dim3 lgrid((NN * 16 + 255) / 256);       // 6250 (16 lanes/node, quad-per-edge)

    count_kernel<<<pgrid, 512, 0, stream>>>(dst, cntmat);
    scan_kernel<<<dim3(NB), 512, 0, stream>>>(cntmat, offT, bucketcnt);
    scatter_kernel<<<pgrid, 512, 0, stream>>>(src, dst, etype, cntmat, offT, tmp);
    pass2_kernel<<<ngrid, 512, 0, stream>>>(tmp, bucketcnt, off2, recs, x, w1, root1, b1, h1b);
    layer2_kernel<<<lgrid, 256, 0, stream>>>(off2, recs, h1b, w2, root2, b2, h2b);
    layer3_kernel<<<lgrid, 256, 0, stream>>>(off2, recs, h2b, w3, root3, b3, out);
}

// Round 7
// 237.045 us; speedup vs baseline: 1.1445x; 1.0009x over previous
//
#include <hip/hip_runtime.h>
#include <math.h>

#define NN 100000
#define NE 3200000
#define NR 90
#define NB 782          // buckets of 128 nodes (dst>>7)
#define CH 4096         // edges per chunk
#define NCHUNK 782      // ceil(NE/CH)
#define CAP 6144        // padded per-bucket capacity (mean 4096, +32 sigma)

typedef unsigned int u32;
typedef unsigned short u16;

__device__ inline u32 pack2(float a, float b) {       // bf16(a) lo16, bf16(b) hi16 (RNE)
    u32 ua = __float_as_uint(a); ua += 0x7FFFu + ((ua >> 16) & 1u);
    u32 ub = __float_as_uint(b); ub += 0x7FFFu + ((ub >> 16) & 1u);
    return (ua >> 16) | (ub & 0xFFFF0000u);
}
__device__ inline float unlo(u32 w) { return __uint_as_float(w << 16); }
__device__ inline float unhi(u32 w) { return __uint_as_float(w & 0xFFFF0000u); }

// ============ pass 1 (deterministic, ZERO global atomics) ============
// P1a: per-chunk histogram -> cntmat[chunk][NB]
__global__ __launch_bounds__(512) void count_kernel(const int* __restrict__ dst,
                                                    u32* __restrict__ cntmat) {
    __shared__ u32 cntA[NB];
    int tid = threadIdx.x;
    int c0 = blockIdx.x * CH;
    int c1 = c0 + CH; if (c1 > NE) c1 = NE;
    for (int i = tid; i < NB; i += 512) cntA[i] = 0;
    __syncthreads();
    for (int e = c0 + tid; e < c1; e += 512)
        atomicAdd(&cntA[(u32)dst[e] >> 7], 1u);
    __syncthreads();
    for (int i = tid; i < NB; i += 512)
        cntmat[(size_t)blockIdx.x * NB + i] = cntA[i];
}

// P1b: per-bucket exclusive scan over chunks -> offT[bucket][NCHUNK]; totals -> bucketcnt
__global__ __launch_bounds__(512) void scan_kernel(const u32* __restrict__ cntmat,
                                                   u32* __restrict__ offT,
                                                   u32* __restrict__ bucketcnt) {
    __shared__ u32 scanS[512];
    int tid = threadIdx.x, b = blockIdx.x;
    int c0 = 2 * tid, c1 = 2 * tid + 1;
    u32 a  = (c0 < NCHUNK) ? cntmat[(size_t)c0 * NB + b] : 0u;
    u32 bb = (c1 < NCHUNK) ? cntmat[(size_t)c1 * NB + b] : 0u;
    scanS[tid] = a + bb;
    __syncthreads();
#pragma unroll
    for (int ofs = 1; ofs < 512; ofs <<= 1) {
        u32 v = (tid >= ofs) ? scanS[tid - ofs] : 0u;
        __syncthreads();
        scanS[tid] += v;
        __syncthreads();
    }
    u32 excl = (tid == 0) ? 0u : scanS[tid - 1];
    if (c0 < NCHUNK) offT[(size_t)b * NCHUNK + c0] = excl;
    if (c1 < NCHUNK) offT[(size_t)b * NCHUNK + c1] = excl + a;
    if (tid == (NCHUNK - 1) / 2) bucketcnt[b] = scanS[(NCHUNK - 1) / 2];
}

// P1c: scatter with precomputed bases; LDS-staged coalesced global write
// tmp entry: (dst&127)<<25 | src<<7 | et ; bucket b's window is tmp[b*CAP ..]
__global__ __launch_bounds__(512) void scatter_kernel(const int* __restrict__ src,
                                                      const int* __restrict__ dst,
                                                      const int* __restrict__ et,
                                                      const u32* __restrict__ cntmat,
                                                      const u32* __restrict__ offT,
                                                      u32* __restrict__ tmp) {
    __shared__ u32 lcur[NB];
    __shared__ u32 delta[NB];
    __shared__ u32 scanS[512];
    __shared__ u32 lrecs[CH];
    __shared__ u16 lbid[CH];
    int tid = threadIdx.x, ck = blockIdx.x;
    int c0 = ck * CH;
    int c1 = c0 + CH; if (c1 > NE) c1 = NE;
    int nloc = c1 - c0;

    int i0 = 2 * tid, i1 = 2 * tid + 1;
    u32 ca = (i0 < NB) ? cntmat[(size_t)ck * NB + i0] : 0u;
    u32 cb = (i1 < NB) ? cntmat[(size_t)ck * NB + i1] : 0u;
    scanS[tid] = ca + cb;
    __syncthreads();
#pragma unroll
    for (int ofs = 1; ofs < 512; ofs <<= 1) {
        u32 v = (tid >= ofs) ? scanS[tid - ofs] : 0u;
        __syncthreads();
        scanS[tid] += v;
        __syncthreads();
    }
    u32 exc = (tid == 0) ? 0u : scanS[tid - 1];
    if (i0 < NB) {
        lcur[i0] = exc;
        delta[i0] = (u32)i0 * CAP + offT[(size_t)i0 * NCHUNK + ck] - exc;
    }
    if (i1 < NB) {
        u32 e1 = exc + ca;
        lcur[i1] = e1;
        delta[i1] = (u32)i1 * CAP + offT[(size_t)i1 * NCHUNK + ck] - e1;
    }
    __syncthreads();

    for (int e = c0 + tid; e < c1; e += 512) {
        u32 d = (u32)dst[e];
        u32 b = d >> 7;
        u32 pos = atomicAdd(&lcur[b], 1u);
        lrecs[pos] = ((d & 127u) << 25) | ((u32)src[e] << 7) | (u32)et[e];
        lbid[pos] = (u16)b;
    }
    __syncthreads();

    for (int k = tid; k < nloc; k += 512)
        tmp[delta[lbid[k]] + k] = lrecs[k];
}

// ---------------- pass 2 + layer 1 fused (512 threads, 128-node bucket) ----------------
#define CNTW (128 * 23)
__global__ __launch_bounds__(512) void pass2_kernel(const u32* __restrict__ tmp,
                                                    const u32* __restrict__ ccursor,
                                                    u32* __restrict__ off2,
                                                    u32* __restrict__ recs,
                                                    const float* __restrict__ x,
                                                    const float* __restrict__ w1,
                                                    const float* __restrict__ root1,
                                                    const float* __restrict__ b1,
                                                    u32* __restrict__ h1b) {   // [NN][4] u32 (8 bf16)
    __shared__ u32 lc2[128];         // per-node cursor (relative)
    __shared__ u32 cnt32[CNTW];      // per-(node,rel) u8 counts packed 4/word
    __shared__ u32 sh[128];          // inclusive degree scan (survives all phases)
    __shared__ u32 lrec[CAP];        // sorted recs mirror for phase E
    __shared__ float w1s[NR * 16];   // bank-rotated w1 (5.76 KB)
    int tid = threadIdx.x;
    int b = blockIdx.x;
    u32 r0 = (u32)b * CAP;
    u32 r1 = r0 + ccursor[b];

    for (int i = tid; i < CNTW; i += 512) cnt32[i] = 0;
    // stage w1 with per-t rotation: slot lin stores w1[t*16 + ((lin - 8*((t>>1)&1)) & 15)]
    for (int i = tid; i < NR * 16; i += 512) {
        int t = i >> 4, lin = i & 15;
        int rel = (lin - (((t >> 1) & 1) * 8)) & 15;
        w1s[i] = w1[t * 16 + rel];
    }
    __syncthreads();

    // A': issue ALL loads first (12 in flight), then consume with atomics
    u32 cached[12];
#pragma unroll
    for (int i = 0; i < 12; i++) {
        u32 k = r0 + (u32)tid + (u32)i * 512u;
        cached[i] = (k < r1) ? tmp[k] : 0xFFFFFFFFu;
    }
#pragma unroll
    for (int i = 0; i < 12; i++) {
        u32 v = cached[i];
        if (v != 0xFFFFFFFFu) {
            u32 ln = v >> 25, rel = v & 127u;
            atomicAdd(&cnt32[ln * 23 + (rel >> 2)], 1u << ((rel & 3u) * 8u));
        }
    }
    __syncthreads();

    // A2: per-node degree = bytewise sum of own 23-word slice
    if (tid < 128) {
        u32 s = 0;
#pragma unroll
        for (int i = 0; i < 23; i++) {
            u32 w = cnt32[tid * 23 + i];
            s += (w & 255u) + ((w >> 8) & 255u) + ((w >> 16) & 255u) + (w >> 24);
        }
        sh[tid] = s;
    }
    __syncthreads();

    // B: inclusive scan of degrees (128 entries)
#pragma unroll
    for (int ofs = 1; ofs < 128; ofs <<= 1) {
        u32 v = (tid >= ofs && tid < 128) ? sh[tid - ofs] : 0u;
        __syncthreads();
        if (tid < 128) sh[tid] += v;
        __syncthreads();
    }
    int n = b * 128 + tid;
    if (tid < 128) {
        u32 excl = (tid == 0) ? 0u : sh[tid - 1];
        u32 deg = sh[tid] - excl;
        if (n < NN) off2[n] = (deg << 23) | (r0 + excl);
        lc2[tid] = excl;
    }
    __syncthreads();

    // C: scatter final recs — embed count byte; mirror into LDS
#pragma unroll
    for (int i = 0; i < 12; i++) {
        u32 v = cached[i];
        if (v != 0xFFFFFFFFu) {
            u32 ln = v >> 25, rel = v & 127u;
            u32 c = (cnt32[ln * 23 + (rel >> 2)] >> ((rel & 3u) * 8u)) & 255u;
            u32 pos = atomicAdd(&lc2[ln], 1u);
            u32 rr = (c << 24) | (v & 0xFFFFFFu);
            recs[r0 + pos] = rr;
            lrec[pos] = rr;
        }
    }
    __syncthreads();

    // E: layer 1 — 16 lanes/node: 8 edge slots x 2 weight-blocks; distributed bf16 epilogue
    for (int g = 0; g < 4; g++) {
        int ln = g * 32 + (tid >> 4);          // 0..127
        int l = tid & 15, e = l >> 1, j = l & 1;
        int nn = b * 128 + ln;
        float a0 = 0.f, a1 = 0.f, a2 = 0.f, a3 = 0.f;
        if (nn < NN) {
            u32 k0l = (ln == 0) ? 0u : sh[ln - 1];
            u32 k1l = sh[ln];
            for (u32 k = k0l + e; k < k1l; k += 8) {
                u32 rec = lrec[k];
                u32 t = rec & 127u, s = (rec >> 7) & 0x1FFFFu;
                float norm = __builtin_amdgcn_rcpf((float)(rec >> 24));
                float2 xv = *(const float2*)(x + (size_t)s * 4 + 2 * j);
                const float* wq = w1s + t * 16 + (((j + ((t >> 1) & 1)) * 8) & 15);
                float4 wA = *(const float4*)wq;
                float4 wB = *(const float4*)(wq + 4);
                float x0 = xv.x * norm, x1 = xv.y * norm;
                a0 += x0 * wA.x + x1 * wB.x;
                a1 += x0 * wA.y + x1 * wB.y;
                a2 += x0 * wA.z + x1 * wB.z;
                a3 += x0 * wA.w + x1 * wB.w;
            }
        }
        a0 += __shfl_xor(a0, 2); a0 += __shfl_xor(a0, 4); a0 += __shfl_xor(a0, 8);
        a1 += __shfl_xor(a1, 2); a1 += __shfl_xor(a1, 4); a1 += __shfl_xor(a1, 8);
        a2 += __shfl_xor(a2, 2); a2 += __shfl_xor(a2, 4); a2 += __shfl_xor(a2, 8);
        a3 += __shfl_xor(a3, 2); a3 += __shfl_xor(a3, 4); a3 += __shfl_xor(a3, 8);
        if (e == 0 && nn < NN) {
            float4 xn = *(const float4*)(x + (size_t)nn * 4);
            int o0 = 4 * j;
            float v0 = fmaxf(a0 + b1[o0]     + xn.x * root1[o0]     + xn.y * root1[8 + o0]
                        + xn.z * root1[16 + o0]     + xn.w * root1[24 + o0], 0.f);
            float v1 = fmaxf(a1 + b1[o0 + 1] + xn.x * root1[o0 + 1] + xn.y * root1[8 + o0 + 1]
                        + xn.z * root1[16 + o0 + 1] + xn.w * root1[24 + o0 + 1], 0.f);
            float v2 = fmaxf(a2 + b1[o0 + 2] + xn.x * root1[o0 + 2] + xn.y * root1[8 + o0 + 2]
                        + xn.z * root1[16 + o0 + 2] + xn.w * root1[24 + o0 + 2], 0.f);
            float v3 = fmaxf(a3 + b1[o0 + 3] + xn.x * root1[o0 + 3] + xn.y * root1[8 + o0 + 3]
                        + xn.z * root1[16 + o0 + 3] + xn.w * root1[24 + o0 + 3], 0.f);
            *(uint2*)(h1b + (size_t)nn * 4 + 2 * j) = make_uint2(pack2(v0, v1), pack2(v2, v3));
        }
    }
}

// ======== layers 2/3: quad-per-edge, bf16 L2-resident tables, LDS rotated weights ========

// ---------------- layer 2: add-aggr + root + bias + relu -> h2b bf16[NN][16] ----------------
// lane j of each quad handles block j: inputs 2j..2j+1 -> outputs 3j..3j+2 (u32 words 2j,2j+1)
__global__ __launch_bounds__(256) void layer2_kernel(
        const u32* __restrict__ off2, const u32* __restrict__ recs,
        const u32* __restrict__ h1b,             // [NN][4] u32 (8 bf16)
        const float* __restrict__ w2, const float* __restrict__ root2,
        const float* __restrict__ b2, u32* __restrict__ h2b) {   // [NN][8] u32 (16 bf16 slots)
    __shared__ float w2s[NR * 32];               // rotated, 6->8 padded (11.5 KB)
    int tid = threadIdx.x;
    for (int i = tid; i < NR * 32; i += 256) {
        int t = i >> 5, lin = i & 31;
        int rel = (lin - ((t * 8) & 31)) & 31;   // = 8*j + slot
        int jj = rel >> 3, slot = rel & 7;
        w2s[i] = (slot < 6) ? w2[t * 24 + jj * 6 + slot] : 0.0f;
    }
    __syncthreads();

    int gid = blockIdx.x * 256 + tid;
    int n = gid >> 4, l = gid & 15, e = l >> 2, j = l & 3;
    if (n >= NN) return;
    u32 ov = off2[n];
    u32 k0 = ov & 0x7FFFFFu, k1 = k0 + (ov >> 23);
    float a0 = 0.f, a1 = 0.f, a2 = 0.f;
#pragma unroll 4
    for (u32 k = k0 + e; k < k1; k += 4) {
        u32 rec = recs[k];
        u32 t = rec & 127u, s = (rec >> 7) & 0x1FFFFu;
        u32 hw = h1b[(size_t)s * 4 + j];          // feats 2j, 2j+1 (bf16 pair)
        float hx = unlo(hw), hy = unhi(hw);
        const float* wq = w2s + t * 32 + ((8 * (j + t)) & 31);
        float4 wa = *(const float4*)wq;          // slots 0..3
        float2 wb = *(const float2*)(wq + 4);    // slots 4..5
        a0 += hx * wa.x + hy * wa.w;
        a1 += hx * wa.y + hy * wb.x;
        a2 += hx * wa.z + hy * wb.y;
    }
    a0 += __shfl_xor(a0, 4); a0 += __shfl_xor(a0, 8);
    a1 += __shfl_xor(a1, 4); a1 += __shfl_xor(a1, 8);
    a2 += __shfl_xor(a2, 4); a2 += __shfl_xor(a2, 8);
    if (e == 0) {
        uint4 hn = *(const uint4*)(h1b + (size_t)n * 4);
        float hv8[8] = { unlo(hn.x), unhi(hn.x), unlo(hn.y), unhi(hn.y),
                         unlo(hn.z), unhi(hn.z), unlo(hn.w), unhi(hn.w) };
        float accv[3] = {a0, a1, a2};
        int o0 = 3 * j;
        float rv[3];
#pragma unroll
        for (int c = 0; c < 3; c++) {
            float v = accv[c] + b2[o0 + c];
#pragma unroll
            for (int i2 = 0; i2 < 8; i2++) v += hv8[i2] * root2[i2 * 12 + o0 + c];
            rv[c] = fmaxf(v, 0.0f);
        }
        *(uint2*)(h2b + (size_t)n * 8 + 2 * j) =
            make_uint2(pack2(rv[0], rv[1]), pack2(rv[2], 0.0f));
    }
}

// ---------------- layer 3: mean-aggr + root + bias + log_softmax ----------------
// lane j handles inputs 3j..3j+2 (u32 words 2j,2j+1) -> partial outputs 2(j>>1), 2(j>>1)+1
__global__ __launch_bounds__(256) void layer3_kernel(
        const u32* __restrict__ off2, const u32* __restrict__ recs,
        const u32* __restrict__ h2b,             // [NN][8] u32 (16 bf16 slots)
        const float* __restrict__ w3, const float* __restrict__ root3,
        const float* __restrict__ b3, float* __restrict__ out) {
    __shared__ float w3s[NR * 32];               // rotated, 6->8 padded (11.5 KB)
    int tid = threadIdx.x;
    for (int i = tid; i < NR * 32; i += 256) {
        int t = i >> 5, lin = i & 31;
        int rel = (lin - ((t * 8) & 31)) & 31;
        int jj = rel >> 3, slot = rel & 7;
        w3s[i] = (slot < 6) ? w3[t * 24 + jj * 6 + slot] : 0.0f;
    }
    __syncthreads();

    int gid = blockIdx.x * 256 + tid;
    int n = gid >> 4, l = gid & 15, e = l >> 2, j = l & 3;
    if (n >= NN) return;
    float a0 = 0.f, a1 = 0.f;
    u32 ov = off2[n];
    u32 k0 = ov & 0x7FFFFFu, k1 = k0 + (ov >> 23);
#pragma unroll 4
    for (u32 k = k0 + e; k < k1; k += 4) {
        u32 rec = recs[k];
        u32 t = rec & 127u, s = (rec >> 7) & 0x1FFFFu;
        float norm = __builtin_amdgcn_rcpf((float)(rec >> 24));
        uint2 hp = *(const uint2*)(h2b + (size_t)s * 8 + 2 * j);   // 3 bf16 feats
        float h0 = unlo(hp.x), h1v = unhi(hp.x), h2v = unlo(hp.y);
        const float* wq = w3s + t * 32 + ((8 * (j + t)) & 31);
        float4 wa = *(const float4*)wq;          // slots 0..3: i0o0 i0o1 i1o0 i1o1
        float2 wb = *(const float2*)(wq + 4);    // slots 4..5: i2o0 i2o1
        float m0 = h0 * wa.x + h1v * wa.z + h2v * wb.x;
        float m1 = h0 * wa.y + h1v * wa.w + h2v * wb.y;
        a0 += m0 * norm;
        a1 += m1 * norm;
    }
    // reduce over edge slots, then merge the two input-halves (j and j^1 share output block)
    a0 += __shfl_xor(a0, 4); a0 += __shfl_xor(a0, 8); a0 += __shfl_xor(a0, 1);
    a1 += __shfl_xor(a1, 4); a1 += __shfl_xor(a1, 8); a1 += __shfl_xor(a1, 1);
    if (e == 0 && (j & 1) == 0) {
        int bb = j >> 1;                          // outputs 2bb, 2bb+1
        const u32* hbn = h2b + (size_t)n * 8;
        uint4 q0 = *(const uint4*)hbn;
        uint4 q1 = *(const uint4*)(hbn + 4);
        float hv[12] = { unlo(q0.x), unhi(q0.x), unlo(q0.y),
                         unlo(q0.z), unhi(q0.z), unlo(q0.w),
                         unlo(q1.x), unhi(q1.x), unlo(q1.y),
                         unlo(q1.z), unhi(q1.z), unlo(q1.w) };
        float v0 = a0 + b3[2 * bb], v1 = a1 + b3[2 * bb + 1];
#pragma unroll
        for (int f = 0; f < 12; f++) {
            v0 += hv[f] * root3[f * 4 + 2 * bb];
            v1 += hv[f] * root3[f * 4 + 2 * bb + 1];
        }
        float mx = fmaxf(v0, v1);
        mx = fmaxf(mx, __shfl_xor(mx, 2));
        float sm = __expf(v0 - mx) + __expf(v1 - mx);
        sm += __shfl_xor(sm, 2);
        float lse = mx + __logf(sm);
        *(float2*)(out + (size_t)n * 4 + 2 * bb) = make_float2(v0 - lse, v1 - lse);
    }
}

extern "C" void kernel_launch(void* const* d_in, const int* in_sizes, int n_in,
                              void* d_out, int out_size, void* d_ws, size_t ws_size,
                              hipStream_t stream) {
    const float* x     = (const float*)d_in[0];
    const int*   ei    = (const int*)d_in[1];   // [2, E]
    const int*   etype = (const int*)d_in[2];
    const float* w1    = (const float*)d_in[3];
    const float* root1 = (const float*)d_in[4];
    const float* b1    = (const float*)d_in[5];
    const float* w2    = (const float*)d_in[6];
    const float* root2 = (const float*)d_in[7];
    const float* b2    = (const float*)d_in[8];
    const float* w3    = (const float*)d_in[9];
    const float* root3 = (const float*)d_in[10];
    const float* b3    = (const float*)d_in[11];
    float* out = (float*)d_out;

    const int* src = ei;
    const int* dst = ei + NE;

    // workspace layout (bytes):
    //   bucketcnt: [NB]     u32   @ 0           (3,128 -> pad 3,200)
    //   off2    : [NN]      u32   @ 3,200       (400,000 -> ends 403,200)
    //   tmp     : [NB*CAP]  u32   @ 403,200     (19,218,432 -> ends 19,621,632)
    //     h2b   : [NN][8]   u32   @ 403,200     (3,200,000) -- overlays tmp (dead after pass2)
    //   recs    : [NB*CAP]  u32   @ 19,621,632  (19,218,432 -> ends 38,840,064)
    //     cntmat: [NCHUNK*NB] u32 @ 19,621,632  (2,446,096) -- overlays recs, dead after P1c
    //     offT  : [NB*NCHUNK] u32 @ 22,067,728  (2,446,096) -- overlays recs, dead after P1c
    //   h1b     : [NN][4]   u32   @ 38,840,064  (1,600,000 -> total 40,440,064)
    char* ws = (char*)d_ws;
    u32*   bucketcnt = (u32*)ws;
    u32*   off2    = (u32*)(ws + 3200);
    u32*   tmp     = (u32*)(ws + 403200);
    u32*   h2b     = (u32*)(ws + 403200);
    u32*   recs    = (u32*)(ws + 19621632);
    u32*   cntmat  = (u32*)(ws + 19621632);
    u32*   offT    = (u32*)(ws + 22067728);
    u32*   h1b     = (u32*)(ws + 38840064);

    dim3 pgrid(NCHUNK);                      // 782
    dim3 ngrid(NB);                          // 782
    dim3 lgrid((NN * 16 + 255) / 256);       // 6250 (16 lanes/node, quad-per-edge)

    count_kernel<<<pgrid, 512, 0, stream>>>(dst, cntmat);
    scan_kernel<<<dim3(NB), 512, 0, stream>>>(cntmat, offT, bucketcnt);
    scatter_kernel<<<pgrid, 512, 0, stream>>>(src, dst, etype, cntmat, offT, tmp);
    pass2_kernel<<<ngrid, 512, 0, stream>>>(tmp, bucketcnt, off2, recs, x, w1, root1, b1, h1b);
    layer2_kernel<<<lgrid, 256, 0, stream>>>(off2, recs, h1b, w2, root2, b2, h2b);
    layer3_kernel<<<lgrid, 256, 0, stream>>>(off2, recs, h2b, w3, root3, b3, out);
}

// Round 8
// 235.106 us; speedup vs baseline: 1.1539x; 1.0082x over previous
//
#include <hip/hip_runtime.h>
#include <math.h>

#define NN 100000
#define NE 3200000
#define NR 90
#define NB 782          // buckets of 128 nodes (dst>>7)
#define CH 4096         // edges per chunk
#define NCHUNK 782      // ceil(NE/CH)
#define CAP 6144        // padded per-bucket capacity (mean 4096, +32 sigma)

typedef unsigned int u32;
typedef unsigned short u16;

__device__ inline u32 pack2(float a, float b) {       // bf16(a) lo16, bf16(b) hi16 (RNE)
    u32 ua = __float_as_uint(a); ua += 0x7FFFu + ((ua >> 16) & 1u);
    u32 ub = __float_as_uint(b); ub += 0x7FFFu + ((ub >> 16) & 1u);
    return (ua >> 16) | (ub & 0xFFFF0000u);
}
__device__ inline float unlo(u32 w) { return __uint_as_float(w << 16); }
__device__ inline float unhi(u32 w) { return __uint_as_float(w & 0xFFFF0000u); }
__device__ inline u32 umin(u32 a, u32 b) { return a < b ? a : b; }

// ============ pass 1 (deterministic, ZERO global atomics) ============
// P1a: per-chunk histogram -> cntmat[chunk][NB]
__global__ __launch_bounds__(512) void count_kernel(const int* __restrict__ dst,
                                                    u32* __restrict__ cntmat) {
    __shared__ u32 cntA[NB];
    int tid = threadIdx.x;
    int c0 = blockIdx.x * CH;
    int c1 = c0 + CH; if (c1 > NE) c1 = NE;
    for (int i = tid; i < NB; i += 512) cntA[i] = 0;
    __syncthreads();
    for (int e = c0 + tid; e < c1; e += 512)
        atomicAdd(&cntA[(u32)dst[e] >> 7], 1u);
    __syncthreads();
    for (int i = tid; i < NB; i += 512)
        cntmat[(size_t)blockIdx.x * NB + i] = cntA[i];
}

// P1b: per-bucket exclusive scan over chunks -> offT[bucket][NCHUNK]; totals -> bucketcnt
__global__ __launch_bounds__(512) void scan_kernel(const u32* __restrict__ cntmat,
                                                   u32* __restrict__ offT,
                                                   u32* __restrict__ bucketcnt) {
    __shared__ u32 scanS[512];
    int tid = threadIdx.x, b = blockIdx.x;
    int c0 = 2 * tid, c1 = 2 * tid + 1;
    u32 a  = (c0 < NCHUNK) ? cntmat[(size_t)c0 * NB + b] : 0u;
    u32 bb = (c1 < NCHUNK) ? cntmat[(size_t)c1 * NB + b] : 0u;
    scanS[tid] = a + bb;
    __syncthreads();
#pragma unroll
    for (int ofs = 1; ofs < 512; ofs <<= 1) {
        u32 v = (tid >= ofs) ? scanS[tid - ofs] : 0u;
        __syncthreads();
        scanS[tid] += v;
        __syncthreads();
    }
    u32 excl = (tid == 0) ? 0u : scanS[tid - 1];
    if (c0 < NCHUNK) offT[(size_t)b * NCHUNK + c0] = excl;
    if (c1 < NCHUNK) offT[(size_t)b * NCHUNK + c1] = excl + a;
    if (tid == (NCHUNK - 1) / 2) bucketcnt[b] = scanS[(NCHUNK - 1) / 2];
}

// P1c: scatter with precomputed bases; LDS-staged coalesced global write
// tmp entry: (dst&127)<<25 | src<<7 | et ; bucket b's window is tmp[b*CAP ..]
__global__ __launch_bounds__(512) void scatter_kernel(const int* __restrict__ src,
                                                      const int* __restrict__ dst,
                                                      const int* __restrict__ et,
                                                      const u32* __restrict__ cntmat,
                                                      const u32* __restrict__ offT,
                                                      u32* __restrict__ tmp) {
    __shared__ u32 lcur[NB];
    __shared__ u32 delta[NB];
    __shared__ u32 scanS[512];
    __shared__ u32 lrecs[CH];
    __shared__ u16 lbid[CH];
    int tid = threadIdx.x, ck = blockIdx.x;
    int c0 = ck * CH;
    int c1 = c0 + CH; if (c1 > NE) c1 = NE;
    int nloc = c1 - c0;

    int i0 = 2 * tid, i1 = 2 * tid + 1;
    u32 ca = (i0 < NB) ? cntmat[(size_t)ck * NB + i0] : 0u;
    u32 cb = (i1 < NB) ? cntmat[(size_t)ck * NB + i1] : 0u;
    scanS[tid] = ca + cb;
    __syncthreads();
#pragma unroll
    for (int ofs = 1; ofs < 512; ofs <<= 1) {
        u32 v = (tid >= ofs) ? scanS[tid - ofs] : 0u;
        __syncthreads();
        scanS[tid] += v;
        __syncthreads();
    }
    u32 exc = (tid == 0) ? 0u : scanS[tid - 1];
    if (i0 < NB) {
        lcur[i0] = exc;
        delta[i0] = (u32)i0 * CAP + offT[(size_t)i0 * NCHUNK + ck] - exc;
    }
    if (i1 < NB) {
        u32 e1 = exc + ca;
        lcur[i1] = e1;
        delta[i1] = (u32)i1 * CAP + offT[(size_t)i1 * NCHUNK + ck] - e1;
    }
    __syncthreads();

    for (int e = c0 + tid; e < c1; e += 512) {
        u32 d = (u32)dst[e];
        u32 b = d >> 7;
        u32 pos = atomicAdd(&lcur[b], 1u);
        lrecs[pos] = ((d & 127u) << 25) | ((u32)src[e] << 7) | (u32)et[e];
        lbid[pos] = (u16)b;
    }
    __syncthreads();

    for (int k = tid; k < nloc; k += 512)
        tmp[delta[lbid[k]] + k] = lrecs[k];
}

// ---------------- pass 2 + layer 1 fused (512 threads, 128-node bucket) ----------------
#define CNTW (128 * 23)
__global__ __launch_bounds__(512) void pass2_kernel(const u32* __restrict__ tmp,
                                                    const u32* __restrict__ ccursor,
                                                    u32* __restrict__ off2,
                                                    u32* __restrict__ recs,
                                                    const float* __restrict__ x,
                                                    const float* __restrict__ w1,
                                                    const float* __restrict__ root1,
                                                    const float* __restrict__ b1,
                                                    u32* __restrict__ h1b) {   // [NN][4] u32 (8 bf16)
    __shared__ u32 lc2[128];         // per-node cursor (relative)
    __shared__ u32 cnt32[CNTW];      // per-(node,rel) u8 counts packed 4/word
    __shared__ u32 sh[128];          // inclusive degree scan (survives all phases)
    __shared__ u32 lrec[CAP];        // sorted recs mirror for phase E
    __shared__ float w1s[NR * 16];   // bank-rotated w1 (5.76 KB)
    int tid = threadIdx.x;
    int b = blockIdx.x;
    u32 r0 = (u32)b * CAP;
    u32 r1 = r0 + ccursor[b];

    for (int i = tid; i < CNTW; i += 512) cnt32[i] = 0;
    // stage w1 with per-t rotation: slot lin stores w1[t*16 + ((lin - 8*((t>>1)&1)) & 15)]
    for (int i = tid; i < NR * 16; i += 512) {
        int t = i >> 4, lin = i & 15;
        int rel = (lin - (((t >> 1) & 1) * 8)) & 15;
        w1s[i] = w1[t * 16 + rel];
    }
    __syncthreads();

    // A': issue ALL loads first (12 in flight), then consume with atomics
    u32 cached[12];
#pragma unroll
    for (int i = 0; i < 12; i++) {
        u32 k = r0 + (u32)tid + (u32)i * 512u;
        cached[i] = (k < r1) ? tmp[k] : 0xFFFFFFFFu;
    }
#pragma unroll
    for (int i = 0; i < 12; i++) {
        u32 v = cached[i];
        if (v != 0xFFFFFFFFu) {
            u32 ln = v >> 25, rel = v & 127u;
            atomicAdd(&cnt32[ln * 23 + (rel >> 2)], 1u << ((rel & 3u) * 8u));
        }
    }
    __syncthreads();

    // A2: per-node degree = bytewise sum of own 23-word slice
    if (tid < 128) {
        u32 s = 0;
#pragma unroll
        for (int i = 0; i < 23; i++) {
            u32 w = cnt32[tid * 23 + i];
            s += (w & 255u) + ((w >> 8) & 255u) + ((w >> 16) & 255u) + (w >> 24);
        }
        sh[tid] = s;
    }
    __syncthreads();

    // B: inclusive scan of degrees (128 entries)
#pragma unroll
    for (int ofs = 1; ofs < 128; ofs <<= 1) {
        u32 v = (tid >= ofs && tid < 128) ? sh[tid - ofs] : 0u;
        __syncthreads();
        if (tid < 128) sh[tid] += v;
        __syncthreads();
    }
    int n = b * 128 + tid;
    if (tid < 128) {
        u32 excl = (tid == 0) ? 0u : sh[tid - 1];
        u32 deg = sh[tid] - excl;
        if (n < NN) off2[n] = (deg << 23) | (r0 + excl);
        lc2[tid] = excl;
    }
    __syncthreads();

    // C: scatter final recs — embed count byte; mirror into LDS
#pragma unroll
    for (int i = 0; i < 12; i++) {
        u32 v = cached[i];
        if (v != 0xFFFFFFFFu) {
            u32 ln = v >> 25, rel = v & 127u;
            u32 c = (cnt32[ln * 23 + (rel >> 2)] >> ((rel & 3u) * 8u)) & 255u;
            u32 pos = atomicAdd(&lc2[ln], 1u);
            u32 rr = (c << 24) | (v & 0xFFFFFFu);
            recs[r0 + pos] = rr;
            lrec[pos] = rr;
        }
    }
    __syncthreads();

    // E: layer 1 — 16 lanes/node: 8 edge slots x 2 weight-blocks; masked gather batches
    for (int g = 0; g < 4; g++) {
        int ln = g * 32 + (tid >> 4);          // 0..127
        int l = tid & 15, e = l >> 1, j = l & 1;
        int nn = b * 128 + ln;
        float a0 = 0.f, a1 = 0.f, a2 = 0.f, a3 = 0.f;
        if (nn < NN) {
            u32 k0l = (ln == 0) ? 0u : sh[ln - 1];
            u32 k1l = sh[ln];
            u32 k1m = k1l - 1;                 // valid only when loop entered
            for (u32 kb = k0l + e; kb < k1l; kb += 32) {
                u32 kB = kb + 8, kC = kb + 16, kD = kb + 24;
                u32 rA = lrec[kb];
                u32 rB = lrec[umin(kB, k1m)];
                u32 rC = lrec[umin(kC, k1m)];
                u32 rD = lrec[umin(kD, k1m)];
                float2 xA = *(const float2*)(x + (size_t)((rA >> 7) & 0x1FFFFu) * 4 + 2 * j);
                float2 xB = *(const float2*)(x + (size_t)((rB >> 7) & 0x1FFFFu) * 4 + 2 * j);
                float2 xC = *(const float2*)(x + (size_t)((rC >> 7) & 0x1FFFFu) * 4 + 2 * j);
                float2 xD = *(const float2*)(x + (size_t)((rD >> 7) & 0x1FFFFu) * 4 + 2 * j);
                float mB = (kB < k1l) ? 1.f : 0.f;
                float mC = (kC < k1l) ? 1.f : 0.f;
                float mD = (kD < k1l) ? 1.f : 0.f;
#define P2E_EDGE(RR, XX, MM)                                                    \
                {                                                               \
                    u32 t = (RR) & 127u;                                        \
                    float norm = __builtin_amdgcn_rcpf((float)((RR) >> 24)) * (MM); \
                    const float* wq = w1s + t * 16 + (((j + ((t >> 1) & 1)) * 8) & 15); \
                    float4 wA = *(const float4*)wq;                             \
                    float4 wB = *(const float4*)(wq + 4);                       \
                    float x0 = (XX).x * norm, x1 = (XX).y * norm;               \
                    a0 += x0 * wA.x + x1 * wB.x;                                \
                    a1 += x0 * wA.y + x1 * wB.y;                                \
                    a2 += x0 * wA.z + x1 * wB.z;                                \
                    a3 += x0 * wA.w + x1 * wB.w;                                \
                }
                P2E_EDGE(rA, xA, 1.f)
                P2E_EDGE(rB, xB, mB)
                P2E_EDGE(rC, xC, mC)
                P2E_EDGE(rD, xD, mD)
#undef P2E_EDGE
            }
        }
        a0 += __shfl_xor(a0, 2); a0 += __shfl_xor(a0, 4); a0 += __shfl_xor(a0, 8);
        a1 += __shfl_xor(a1, 2); a1 += __shfl_xor(a1, 4); a1 += __shfl_xor(a1, 8);
        a2 += __shfl_xor(a2, 2); a2 += __shfl_xor(a2, 4); a2 += __shfl_xor(a2, 8);
        a3 += __shfl_xor(a3, 2); a3 += __shfl_xor(a3, 4); a3 += __shfl_xor(a3, 8);
        if (e == 0 && nn < NN) {
            float4 xn = *(const float4*)(x + (size_t)nn * 4);
            int o0 = 4 * j;
            float v0 = fmaxf(a0 + b1[o0]     + xn.x * root1[o0]     + xn.y * root1[8 + o0]
                        + xn.z * root1[16 + o0]     + xn.w * root1[24 + o0], 0.f);
            float v1 = fmaxf(a1 + b1[o0 + 1] + xn.x * root1[o0 + 1] + xn.y * root1[8 + o0 + 1]
                        + xn.z * root1[16 + o0 + 1] + xn.w * root1[24 + o0 + 1], 0.f);
            float v2 = fmaxf(a2 + b1[o0 + 2] + xn.x * root1[o0 + 2] + xn.y * root1[8 + o0 + 2]
                        + xn.z * root1[16 + o0 + 2] + xn.w * root1[24 + o0 + 2], 0.f);
            float v3 = fmaxf(a3 + b1[o0 + 3] + xn.x * root1[o0 + 3] + xn.y * root1[8 + o0 + 3]
                        + xn.z * root1[16 + o0 + 3] + xn.w * root1[24 + o0 + 3], 0.f);
            *(uint2*)(h1b + (size_t)nn * 4 + 2 * j) = make_uint2(pack2(v0, v1), pack2(v2, v3));
        }
    }
}

// ======== layers 2/3: quad-per-edge, bf16 L2-resident tables, masked gather batches ========

// ---------------- layer 2: add-aggr + root + bias + relu -> h2b bf16[NN][16] ----------------
// lane j of each quad handles block j: inputs 2j..2j+1 -> outputs 3j..3j+2 (u32 words 2j,2j+1)
__global__ __launch_bounds__(256) void layer2_kernel(
        const u32* __restrict__ off2, const u32* __restrict__ recs,
        const u32* __restrict__ h1b,             // [NN][4] u32 (8 bf16)
        const float* __restrict__ w2, const float* __restrict__ root2,
        const float* __restrict__ b2, u32* __restrict__ h2b) {   // [NN][8] u32 (16 bf16 slots)
    __shared__ float w2s[NR * 32];               // rotated, 6->8 padded (11.5 KB)
    int tid = threadIdx.x;
    for (int i = tid; i < NR * 32; i += 256) {
        int t = i >> 5, lin = i & 31;
        int rel = (lin - ((t * 8) & 31)) & 31;   // = 8*j + slot
        int jj = rel >> 3, slot = rel & 7;
        w2s[i] = (slot < 6) ? w2[t * 24 + jj * 6 + slot] : 0.0f;
    }
    __syncthreads();

    int gid = blockIdx.x * 256 + tid;
    int n = gid >> 4, l = gid & 15, e = l >> 2, j = l & 3;
    if (n >= NN) return;
    u32 ov = off2[n];
    u32 k0 = ov & 0x7FFFFFu, k1 = k0 + (ov >> 23);
    float a0 = 0.f, a1 = 0.f, a2 = 0.f;
    u32 k1m = k1 - 1;                            // valid only when loop entered
    for (u32 kb = k0 + e; kb < k1; kb += 16) {
        u32 kB = kb + 4, kC = kb + 8, kD = kb + 12;
        u32 rA = recs[kb];
        u32 rB = recs[umin(kB, k1m)];
        u32 rC = recs[umin(kC, k1m)];
        u32 rD = recs[umin(kD, k1m)];
        u32 hA = h1b[(size_t)((rA >> 7) & 0x1FFFFu) * 4 + j];
        u32 hB = h1b[(size_t)((rB >> 7) & 0x1FFFFu) * 4 + j];
        u32 hC = h1b[(size_t)((rC >> 7) & 0x1FFFFu) * 4 + j];
        u32 hD = h1b[(size_t)((rD >> 7) & 0x1FFFFu) * 4 + j];
        float mB = (kB < k1) ? 1.f : 0.f;
        float mC = (kC < k1) ? 1.f : 0.f;
        float mD = (kD < k1) ? 1.f : 0.f;
#define L2_EDGE(RR, HH, MM)                                                     \
        {                                                                       \
            u32 t = (RR) & 127u;                                               \
            const float* wq = w2s + t * 32 + ((8 * (j + t)) & 31);             \
            float4 wa = *(const float4*)wq;                                     \
            float2 wb = *(const float2*)(wq + 4);                               \
            float hx = unlo(HH) * (MM), hy = unhi(HH) * (MM);                   \
            a0 += hx * wa.x + hy * wa.w;                                        \
            a1 += hx * wa.y + hy * wb.x;                                        \
            a2 += hx * wa.z + hy * wb.y;                                        \
        }
        L2_EDGE(rA, hA, 1.f)
        L2_EDGE(rB, hB, mB)
        L2_EDGE(rC, hC, mC)
        L2_EDGE(rD, hD, mD)
#undef L2_EDGE
    }
    a0 += __shfl_xor(a0, 4); a0 += __shfl_xor(a0, 8);
    a1 += __shfl_xor(a1, 4); a1 += __shfl_xor(a1, 8);
    a2 += __shfl_xor(a2, 4); a2 += __shfl_xor(a2, 8);
    if (e == 0) {
        uint4 hn = *(const uint4*)(h1b + (size_t)n * 4);
        float hv8[8] = { unlo(hn.x), unhi(hn.x), unlo(hn.y), unhi(hn.y),
                         unlo(hn.z), unhi(hn.z), unlo(hn.w), unhi(hn.w) };
        float accv[3] = {a0, a1, a2};
        int o0 = 3 * j;
        float rv[3];
#pragma unroll
        for (int c = 0; c < 3; c++) {
            float v = accv[c] + b2[o0 + c];
#pragma unroll
            for (int i2 = 0; i2 < 8; i2++) v += hv8[i2] * root2[i2 * 12 + o0 + c];
            rv[c] = fmaxf(v, 0.0f);
        }
        *(uint2*)(h2b + (size_t)n * 8 + 2 * j) =
            make_uint2(pack2(rv[0], rv[1]), pack2(rv[2], 0.0f));
    }
}

// ---------------- layer 3: mean-aggr + root + bias + log_softmax ----------------
// lane j handles inputs 3j..3j+2 (u32 words 2j,2j+1) -> partial outputs 2(j>>1), 2(j>>1)+1
__global__ __launch_bounds__(256) void layer3_kernel(
        const u32* __restrict__ off2, const u32* __restrict__ recs,
        const u32* __restrict__ h2b,             // [NN][8] u32 (16 bf16 slots)
        const float* __restrict__ w3, const float* __restrict__ root3,
        const float* __restrict__ b3, float* __restrict__ out) {
    __shared__ float w3s[NR * 32];               // rotated, 6->8 padded (11.5 KB)
    int tid = threadIdx.x;
    for (int i = tid; i < NR * 32; i += 256) {
        int t = i >> 5, lin = i & 31;
        int rel = (lin - ((t * 8) & 31)) & 31;
        int jj = rel >> 3, slot = rel & 7;
        w3s[i] = (slot < 6) ? w3[t * 24 + jj * 6 + slot] : 0.0f;
    }
    __syncthreads();

    int gid = blockIdx.x * 256 + tid;
    int n = gid >> 4, l = gid & 15, e = l >> 2, j = l & 3;
    if (n >= NN) return;
    float a0 = 0.f, a1 = 0.f;
    u32 ov = off2[n];
    u32 k0 = ov & 0x7FFFFFu, k1 = k0 + (ov >> 23);
    u32 k1m = k1 - 1;                            // valid only when loop entered
    for (u32 kb = k0 + e; kb < k1; kb += 16) {
        u32 kB = kb + 4, kC = kb + 8, kD = kb + 12;
        u32 rA = recs[kb];
        u32 rB = recs[umin(kB, k1m)];
        u32 rC = recs[umin(kC, k1m)];
        u32 rD = recs[umin(kD, k1m)];
        uint2 hA = *(const uint2*)(h2b + (size_t)((rA >> 7) & 0x1FFFFu) * 8 + 2 * j);
        uint2 hB = *(const uint2*)(h2b + (size_t)((rB >> 7) & 0x1FFFFu) * 8 + 2 * j);
        uint2 hC = *(const uint2*)(h2b + (size_t)((rC >> 7) & 0x1FFFFu) * 8 + 2 * j);
        uint2 hD = *(const uint2*)(h2b + (size_t)((rD >> 7) & 0x1FFFFu) * 8 + 2 * j);
        float mB = (kB < k1) ? 1.f : 0.f;
        float mC = (kC < k1) ? 1.f : 0.f;
        float mD = (kD < k1) ? 1.f : 0.f;
#define L3_EDGE(RR, HH, MM)                                                     \
        {                                                                       \
            u32 t = (RR) & 127u;                                               \
            float norm = __builtin_amdgcn_rcpf((float)((RR) >> 24)) * (MM);     \
            const float* wq = w3s + t * 32 + ((8 * (j + t)) & 31);             \
            float4 wa = *(const float4*)wq;                                     \
            float2 wb = *(const float2*)(wq + 4);                               \
            float h0 = unlo((HH).x), h1v = unhi((HH).x), h2v = unlo((HH).y);    \
            float m0 = h0 * wa.x + h1v * wa.z + h2v * wb.x;                     \
            float m1 = h0 * wa.y + h1v * wa.w + h2v * wb.y;                     \
            a0 += m0 * norm;                                                    \
            a1 += m1 * norm;                                                    \
        }
        L3_EDGE(rA, hA, 1.f)
        L3_EDGE(rB, hB, mB)
        L3_EDGE(rC, hC, mC)
        L3_EDGE(rD, hD, mD)
#undef L3_EDGE
    }
    // reduce over edge slots, then merge the two input-halves (j and j^1 share output block)
    a0 += __shfl_xor(a0, 4); a0 += __shfl_xor(a0, 8); a0 += __shfl_xor(a0, 1);
    a1 += __shfl_xor(a1, 4); a1 += __shfl_xor(a1, 8); a1 += __shfl_xor(a1, 1);
    if (e == 0 && (j & 1) == 0) {
        int bb = j >> 1;                          // outputs 2bb, 2bb+1
        const u32* hbn = h2b + (size_t)n * 8;
        uint4 q0 = *(const uint4*)hbn;
        uint4 q1 = *(const uint4*)(hbn + 4);
        float hv[12] = { unlo(q0.x), unhi(q0.x), unlo(q0.y),
                         unlo(q0.z), unhi(q0.z), unlo(q0.w),
                         unlo(q1.x), unhi(q1.x), unlo(q1.y),
                         unlo(q1.z), unhi(q1.z), unlo(q1.w) };
        float v0 = a0 + b3[2 * bb], v1 = a1 + b3[2 * bb + 1];
#pragma unroll
        for (int f = 0; f < 12; f++) {
            v0 += hv[f] * root3[f * 4 + 2 * bb];
            v1 += hv[f] * root3[f * 4 + 2 * bb + 1];
        }
        float mx = fmaxf(v0, v1);
        mx = fmaxf(mx, __shfl_xor(mx, 2));
        float sm = __expf(v0 - mx) + __expf(v1 - mx);
        sm += __shfl_xor(sm, 2);
        float lse = mx + __logf(sm);
        *(float2*)(out + (size_t)n * 4 + 2 * bb) = make_float2(v0 - lse, v1 - lse);
    }
}

extern "C" void kernel_launch(void* const* d_in, const int* in_sizes, int n_in,
                              void* d_out, int out_size, void* d_ws, size_t ws_size,
                              hipStream_t stream) {
    const float* x     = (const float*)d_in[0];
    const int*   ei    = (const int*)d_in[1];   // [2, E]
    const int*   etype = (const int*)d_in[2];
    const float* w1    = (const float*)d_in[3];
    const float* root1 = (const float*)d_in[4];
    const float* b1    = (const float*)d_in[5];
    const float* w2    = (const float*)d_in[6];
    const float* root2 = (const float*)d_in[7];
    const float* b2    = (const float*)d_in[8];
    const float* w3    = (const float*)d_in[9];
    const float* root3 = (const float*)d_in[10];
    const float* b3    = (const float*)d_in[11];
    float* out = (float*)d_out;

    const int* src = ei;
    const int* dst = ei + NE;

    // workspace layout (bytes):
    //   bucketcnt: [NB]     u32   @ 0           (3,128 -> pad 3,200)
    //   off2    : [NN]      u32   @ 3,200       (400,000 -> ends 403,200)
    //   tmp     : [NB*CAP]  u32   @ 403,200     (19,218,432 -> ends 19,621,632)
    //     h2b   : [NN][8]   u32   @ 403,200     (3,200,000) -- overlays tmp (dead after pass2)
    //   recs    : [NB*CAP]  u32   @ 19,621,632  (19,218,432 -> ends 38,840,064)
    //     cntmat: [NCHUNK*NB] u32 @ 19,621,632  (2,446,096) -- overlays recs, dead after P1c
    //     offT  : [NB*NCHUNK] u32 @ 22,067,728  (2,446,096) -- overlays recs, dead after P1c
    //   h1b     : [NN][4]   u32   @ 38,840,064  (1,600,000 -> total 40,440,064)
    char* ws = (char*)d_ws;
    u32*   bucketcnt = (u32*)ws;
    u32*   off2    = (u32*)(ws + 3200);
    u32*   tmp     = (u32*)(ws + 403200);
    u32*   h2b     = (u32*)(ws + 403200);
    u32*   recs    = (u32*)(ws + 19621632);
    u32*   cntmat  = (u32*)(ws + 19621632);
    u32*   offT    = (u32*)(ws + 22067728);
    u32*   h1b     = (u32*)(ws + 38840064);

    dim3 pgrid(NCHUNK);                      // 782
    dim3 ngrid(NB);                          // 782
    dim3 lgrid((NN * 16 + 255) / 256);       // 6250 (16 lanes/node, quad-per-edge)

    count_kernel<<<pgrid, 512, 0, stream>>>(dst, cntmat);
    scan_kernel<<<dim3(NB), 512, 0, stream>>>(cntmat, offT, bucketcnt);
    scatter_kernel<<<pgrid, 512, 0, stream>>>(src, dst, etype, cntmat, offT, tmp);
    pass2_kernel<<<ngrid, 512, 0, stream>>>(tmp, bucketcnt, off2, recs, x, w1, root1, b1, h1b);
    layer2_kernel<<<lgrid, 256, 0, stream>>>(off2, recs, h1b, w2, root2, b2, h2b);
    layer3_kernel<<<lgrid, 256, 0, stream>>>(off2, recs, h2b, w3, root3, b3, out);
}